// Round 6
// baseline (6456.363 us; speedup 1.0000x reference)
//
#include <hip/hip_runtime.h>
#include <math.h>

typedef __attribute__((ext_vector_type(8))) short short8;
typedef __attribute__((ext_vector_type(4))) float f32x4;
typedef unsigned int uint;
typedef unsigned short ushort;

__device__ __forceinline__ ushort f2bf(float f) {
  union { float f; uint u; } v; v.f = f;
  uint u = v.u;
  uint r = (u + 0x7FFFu + ((u >> 16) & 1u)) >> 16;
  return (ushort)r;
}
__device__ __forceinline__ float bflo(uint u) { union { uint u; float f; } v; v.u = u << 16; return v.f; }
__device__ __forceinline__ float bfhi(uint u) { union { uint u; float f; } v; v.u = u & 0xFFFF0000u; return v.f; }
__device__ __forceinline__ uint packbf(float a, float b) { return (uint)f2bf(a) | ((uint)f2bf(b) << 16); }

// ---------------- CSR construction ----------------

static __global__ void k_count(const int* __restrict__ col, int* __restrict__ cnt, int E) {
  int e = blockIdx.x * blockDim.x + threadIdx.x;
  if (e < E) atomicAdd(&cnt[col[e]], 1);
}

static __global__ void k_dinv(const int* __restrict__ cnt, float* __restrict__ dinv, int N) {
  int v = blockIdx.x * blockDim.x + threadIdx.x;
  if (v < N) dinv[v] = rsqrtf((float)cnt[v] + 1.0f);  // +1 = self-loop
}

// two-level scan: thread-serial chunk + wave shuffle scan + wave-sum scan
static __global__ __launch_bounds__(1024) void k_scan(const int* __restrict__ cnt,
                                                      int* __restrict__ rowptr, int N) {
  const int t = threadIdx.x;
  const int per = (N + 1023) / 1024;
  int lo = t * per, hi = min(lo + per, N);
  if (lo > N) lo = N;
  if (hi < lo) hi = lo;
  int sum = 0;
  for (int i = lo; i < hi; ++i) sum += cnt[i];
  int lane = t & 63, w = t >> 6;
  int v = sum;
#pragma unroll
  for (int d = 1; d < 64; d <<= 1) {
    int u = __shfl_up(v, d, 64);
    if (lane >= d) v += u;
  }
  __shared__ int wsum[16];
  if (lane == 63) wsum[w] = v;
  __syncthreads();
  if (t < 16) {
    int x = wsum[t];
#pragma unroll
    for (int d = 1; d < 16; d <<= 1) {
      int u = __shfl_up(x, d, 64);
      if (t >= d) x += u;
    }
    wsum[t] = x;  // inclusive over waves
  }
  __syncthreads();
  int base = (w ? wsum[w - 1] : 0) + v - sum;  // exclusive prefix of this thread's chunk
  int run = base;
  for (int i = lo; i < hi; ++i) { rowptr[i] = run; run += cnt[i]; }
  if (t == 1023) rowptr[N] = run;  // empty tail chunks carry base == total
}

static __global__ void k_fill(const int* __restrict__ row, const int* __restrict__ col,
                              const float* __restrict__ dinv, const int* __restrict__ rowptr,
                              int* __restrict__ fillc, int* __restrict__ csr_src,
                              float* __restrict__ csr_w, int E) {
  int e = blockIdx.x * blockDim.x + threadIdx.x;
  if (e >= E) return;
  int s = row[e], d = col[e];
  int pos = rowptr[d] + atomicAdd(&fillc[d], 1);
  csr_src[pos] = s;
  csr_w[pos] = dinv[s] * dinv[d];
}

// ---------------- weight prep: W[K,Nc] fp32 -> Wt[n][kpad] bf16 (n-major, K zero-padded) ----

static __global__ void k_wprep(const float* __restrict__ W, ushort* __restrict__ Wt,
                               int K, int Kpad, int Nc) {
  int l = blockIdx.y;
  int idx = blockIdx.x * 256 + threadIdx.x;
  if (idx >= Nc * Kpad) return;
  int n = idx / Kpad, k = idx - n * Kpad;
  const float* Wl = W + (size_t)l * K * Nc;
  ushort* Wtl = Wt + (size_t)l * Nc * Kpad;
  Wtl[idx] = (k < K) ? f2bf(Wl[(size_t)k * Nc + n]) : (ushort)0;
}

// ---------------- fused conv: Y = (A_hat X) W + b  (aggregate-first) ----------------
// Xin: [Mpad][KPAD] bf16 post-activation; Bt: [128 n][KPAD] bf16.
// Phase A: gather-aggregate 128 dest rows into LDS A-tile (bf16).
// Phase B: MFMA A-tile x W -> 128x128 tile; bias + act; write.

template <int KPAD>
static __global__ __launch_bounds__(256) void k_conv(
    const ushort* __restrict__ Xin, const ushort* __restrict__ Bt,
    const int* __restrict__ rowptr, const int* __restrict__ csr_src,
    const float* __restrict__ csr_w, const float* __restrict__ dinv,
    const float* __restrict__ bias,
    float* __restrict__ outF, int actF,    // fp32 [N][128] (nullable); actF: 2 = tanh
    ushort* __restrict__ outB, int reluB,  // bf16 [Mpad][128] (nullable)
    int N) {
  constexpr int KU = KPAD / 2;    // uints per input row
  constexpr int STR = KPAD + 8;   // LDS row stride in ushorts (keeps b128 reads conflict-free)
  constexpr int STRU = STR / 2;
  constexpr int K8 = KPAD / 8;
  __shared__ ushort As[128 * STR];
  __shared__ ushort Bs[128 * STR];
  const int tid = threadIdx.x;
  const int lane = tid & 63;
  const int wave = tid >> 6;
  const int bm = blockIdx.x * 128;

  // stage W (loads overlap the gather below; barrier before MFMA covers both)
  for (int ii = tid; ii < 128 * K8; ii += 256) {
    int r = ii / K8, o = ii - r * K8;
    *(short8*)(Bs + r * STR + o * 8) = *(const short8*)(Bt + (size_t)r * KPAD + o * 8);
  }

  const uint* __restrict__ Xu = (const uint*)Xin;
  uint* AsU = (uint*)As;

  if constexpr (KU <= 64) {
    constexpr int NPI = 64 / KU;  // nodes per wave-iteration (1 for KU=64, 4 for KU=16)
    const int c = lane % KU;
    const int sub = lane / KU;
    for (int j = wave * 32 + sub; j < (wave + 1) * 32; j += NPI) {
      int nd = bm + j;
      float a0 = 0.f, a1 = 0.f;
      if (nd < N) {
        float dv = dinv[nd];
        float wsl = dv * dv;
        uint u = Xu[(size_t)nd * KU + c];
        a0 = wsl * bflo(u);
        a1 = wsl * bfhi(u);
        int s = rowptr[nd], e = rowptr[nd + 1];
        int i = s;
        for (; i + 4 <= e; i += 4) {
          int s0 = csr_src[i], s1 = csr_src[i + 1], s2 = csr_src[i + 2], s3 = csr_src[i + 3];
          float w0 = csr_w[i], w1 = csr_w[i + 1], w2 = csr_w[i + 2], w3 = csr_w[i + 3];
          uint u0 = Xu[(size_t)s0 * KU + c];
          uint u1 = Xu[(size_t)s1 * KU + c];
          uint u2 = Xu[(size_t)s2 * KU + c];
          uint u3 = Xu[(size_t)s3 * KU + c];
          a0 += w0 * bflo(u0) + w1 * bflo(u1) + w2 * bflo(u2) + w3 * bflo(u3);
          a1 += w0 * bfhi(u0) + w1 * bfhi(u1) + w2 * bfhi(u2) + w3 * bfhi(u3);
        }
        for (; i < e; ++i) {
          float w0 = csr_w[i];
          uint u0 = Xu[(size_t)csr_src[i] * KU + c];
          a0 += w0 * bflo(u0);
          a1 += w0 * bfhi(u0);
        }
      }
      AsU[j * STRU + c] = packbf(a0, a1);
    }
  } else {
    // KU == 80: lane covers uint c0=lane; lanes<16 also cover c1=lane+64
    for (int j = wave * 32; j < (wave + 1) * 32; ++j) {
      int nd = bm + j;
      float a0 = 0.f, a1 = 0.f, b0 = 0.f, b1 = 0.f;
      const int c0 = lane, c1 = lane + 64;
      const bool has2 = lane < (KU - 64);
      if (nd < N) {
        float dv = dinv[nd];
        float wsl = dv * dv;
        uint u = Xu[(size_t)nd * KU + c0];
        a0 = wsl * bflo(u);
        a1 = wsl * bfhi(u);
        if (has2) {
          uint u2 = Xu[(size_t)nd * KU + c1];
          b0 = wsl * bflo(u2);
          b1 = wsl * bfhi(u2);
        }
        int s = rowptr[nd], e = rowptr[nd + 1];
        for (int i = s; i < e; ++i) {
          int sv = csr_src[i];
          float w0 = csr_w[i];
          uint u0 = Xu[(size_t)sv * KU + c0];
          a0 += w0 * bflo(u0);
          a1 += w0 * bfhi(u0);
          if (has2) {
            uint u2 = Xu[(size_t)sv * KU + c1];
            b0 += w0 * bflo(u2);
            b1 += w0 * bfhi(u2);
          }
        }
      }
      AsU[j * STRU + c0] = packbf(a0, a1);
      if (has2) AsU[j * STRU + c1] = packbf(b0, b1);
    }
  }
  __syncthreads();

  // ---- MFMA phase (structure identical to round-3 verified GEMM) ----
  const int wr = wave >> 1, wc = wave & 1;
  const int l15 = lane & 15, lk = lane >> 4;
  f32x4 acc[4][4];
#pragma unroll
  for (int i = 0; i < 4; ++i)
#pragma unroll
    for (int j = 0; j < 4; ++j) acc[i][j] = (f32x4){0.f, 0.f, 0.f, 0.f};

#pragma unroll
  for (int k0 = 0; k0 < KPAD; k0 += 32) {
    short8 af[4], bfr[4];
#pragma unroll
    for (int i = 0; i < 4; ++i) {
      af[i]  = *(const short8*)(As + (wr * 64 + i * 16 + l15) * STR + k0 + lk * 8);
      bfr[i] = *(const short8*)(Bs + (wc * 64 + i * 16 + l15) * STR + k0 + lk * 8);
    }
#pragma unroll
    for (int i = 0; i < 4; ++i)
#pragma unroll
      for (int j = 0; j < 4; ++j)
        acc[i][j] = __builtin_amdgcn_mfma_f32_16x16x32_bf16(af[i], bfr[j], acc[i][j], 0, 0, 0);
  }

  // epilogue: C/D layout col = lane&15, row = (lane>>4)*4 + reg
#pragma unroll
  for (int i = 0; i < 4; ++i) {
#pragma unroll
    for (int r = 0; r < 4; ++r) {
      int row = bm + wr * 64 + i * 16 + lk * 4 + r;
      if (row >= N) continue;
#pragma unroll
      for (int j = 0; j < 4; ++j) {
        int col = wc * 64 + j * 16 + l15;
        float v = acc[i][j][r] + bias[col];
        if (outF) {
          outF[(size_t)row * 128 + col] = (actF == 2) ? tanhf(v) : v;
        }
        if (outB) {
          outB[(size_t)row * 128 + col] = f2bf(reluB ? fmaxf(v, 0.f) : v);
        }
      }
    }
  }
}

// ---------------- small GEMM: Y[M,4] = A16[M,128] @ W[128,4] fp32 out ----------------

static __global__ __launch_bounds__(256) void k_gemm_small(
    const ushort* __restrict__ A, const float* __restrict__ W, float* __restrict__ Y, int M) {
  __shared__ float Ws[512];
  int tid = threadIdx.x;
  for (int i = tid; i < 512; i += 256) Ws[i] = W[i];
  __syncthreads();
  int m = blockIdx.x * 256 + tid;
  if (m >= M) return;
  const uint* a = (const uint*)(A + (size_t)m * 128);
  float a0 = 0, a1 = 0, a2 = 0, a3 = 0;
#pragma unroll 8
  for (int k2 = 0; k2 < 64; ++k2) {
    uint u = a[k2];
    float x0 = bflo(u), x1 = bfhi(u);
    const float* w = Ws + k2 * 8;
    a0 += x0 * w[0] + x1 * w[4];
    a1 += x0 * w[1] + x1 * w[5];
    a2 += x0 * w[2] + x1 * w[6];
    a3 += x0 * w[3] + x1 * w[7];
  }
  float* y = Y + (size_t)m * 4;
  y[0] = a0; y[1] = a1; y[2] = a2; y[3] = a3;
}

// ---------------- aggregation fp32, small C (C=4) ----------------

static __global__ void k_agg_f32(const float* __restrict__ Hm, float* __restrict__ Y,
                                 const int* __restrict__ rowptr, const int* __restrict__ csr_src,
                                 const float* __restrict__ csr_w, const float* __restrict__ dinv,
                                 const float* __restrict__ bias, int N, int C) {
  int idx = blockIdx.x * blockDim.x + threadIdx.x;
  if (idx >= N * C) return;
  int v = idx / C, c = idx - v * C;
  float dv = dinv[v];
  float acc = dv * dv * Hm[(size_t)v * C + c];
  int s = rowptr[v], e = rowptr[v + 1];
  for (int i = s; i < e; ++i) acc += csr_w[i] * Hm[(size_t)csr_src[i] * C + c];
  Y[idx] = acc + bias[c];
}

// ---------------- instance norm (two-stage, coalesced, atomic-free) ----------------

static __global__ __launch_bounds__(256) void k_in_part(const float* __restrict__ X,
                                                        float* __restrict__ partial, int N) {
  int tid = threadIdx.x;
  int c4 = (tid & 31) * 4;
  int rsub = tid >> 5;  // 0..7
  int row0 = blockIdx.x * 512 + rsub;
  int rowEnd = min(blockIdx.x * 512 + 512, N);
  float s0 = 0, s1 = 0, s2 = 0, s3 = 0, q0 = 0, q1 = 0, q2 = 0, q3 = 0;
  for (int r = row0; r < rowEnd; r += 8) {
    float4 v = *(const float4*)(X + (size_t)r * 128 + c4);
    s0 += v.x; s1 += v.y; s2 += v.z; s3 += v.w;
    q0 += v.x * v.x; q1 += v.y * v.y; q2 += v.z * v.z; q3 += v.w * v.w;
  }
  __shared__ float sb[8][132], qb[8][132];
  sb[rsub][c4] = s0; sb[rsub][c4 + 1] = s1; sb[rsub][c4 + 2] = s2; sb[rsub][c4 + 3] = s3;
  qb[rsub][c4] = q0; qb[rsub][c4 + 1] = q1; qb[rsub][c4 + 2] = q2; qb[rsub][c4 + 3] = q3;
  __syncthreads();
  if (tid < 128) {
    float ss = 0, qq = 0;
#pragma unroll
    for (int g = 0; g < 8; ++g) { ss += sb[g][tid]; qq += qb[g][tid]; }
    partial[(size_t)blockIdx.x * 256 + tid] = ss;
    partial[(size_t)blockIdx.x * 256 + 128 + tid] = qq;
  }
}

static __global__ void k_in_fin(const float* __restrict__ partial, int NB,
                                float* __restrict__ meanv, float* __restrict__ scalev, int N) {
  int c = threadIdx.x;
  if (c >= 128) return;
  float s = 0, q = 0;
  for (int b = 0; b < NB; ++b) {
    s += partial[(size_t)b * 256 + c];
    q += partial[(size_t)b * 256 + 128 + c];
  }
  float m = s / (float)N;
  float var = q / (float)N - m * m;
  meanv[c] = m;
  scalev[c] = rsqrtf(var + 1e-5f);
}

// apply + relu + bf16 cast (stride 128)
static __global__ void k_in_apply(const float* __restrict__ X, const float* __restrict__ meanv,
                                  const float* __restrict__ scalev, ushort* __restrict__ outB, int N) {
  int idx = blockIdx.x * blockDim.x + threadIdx.x;
  if (idx >= N * 64) return;
  int c2 = idx & 63;
  float2 x = *(const float2*)(X + (size_t)idx * 2);
  float2 mm = *(const float2*)(meanv + c2 * 2);
  float2 sc = *(const float2*)(scalev + c2 * 2);
  float o0 = fmaxf((x.x - mm.x) * sc.x, 0.f);
  float o1 = fmaxf((x.y - mm.y) * sc.y, 0.f);
  ((uint*)outB)[idx] = packbf(o0, o1);
}

// ---------------- misc elementwise ----------------

static __global__ void k_cast_mesh0(const float* __restrict__ MF, ushort* __restrict__ C32, int N) {
  int idx = blockIdx.x * blockDim.x + threadIdx.x;  // over N*16 uints (stride 32 bf16)
  if (idx >= N * 16) return;
  int v = idx >> 4, c2 = idx & 15;
  int c = c2 * 2;
  float x0 = 0.f, x1 = 0.f;
  if (c < 8) { x0 = MF[v * 8 + c]; x1 = MF[v * 8 + c + 1]; }
  ((uint*)C32)[idx] = packbf(x0, x1);
}

static __global__ void k_concat16(const float* __restrict__ F, const float* __restrict__ meshL,
                                  ushort* __restrict__ C160, int N) {
  int idx = blockIdx.x * blockDim.x + threadIdx.x;  // over N*80 uints (stride 160 bf16)
  if (idx >= N * 80) return;
  int v = idx / 80, c2 = idx - v * 80;
  int c = c2 * 2;
  float x0 = 0.f, x1 = 0.f;
  if (c < 4) { x0 = F[v * 4 + c]; x1 = F[v * 4 + c + 1]; }
  else if (c < 132) { float2 m = *(const float2*)(meshL + (size_t)v * 128 + (c - 4)); x0 = m.x; x1 = m.y; }
  ((uint*)C160)[idx] = packbf(x0, x1);
}

static __global__ void k_copy(const float* __restrict__ A, float* __restrict__ B, int n) {
  int i = blockIdx.x * blockDim.x + threadIdx.x;
  if (i < n) B[i] = A[i];
}

static __global__ void k_step_finish(const float* __restrict__ fdot_pre,
                                     const float* __restrict__ Fcur, float* __restrict__ Fnext,
                                     float* __restrict__ out, int N, int T, int t) {
  int idx = blockIdx.x * blockDim.x + threadIdx.x;
  if (idx >= N * 4) return;
  int v = idx >> 2, f = idx & 3;
  float fd = tanhf(fdot_pre[idx]);
  float fn = tanhf(Fcur[idx] + fd * 0.1f);  // DT = 0.1
  Fnext[idx] = fn;
  out[((size_t)v * T + t) * 4 + f] = fn;
  out[(size_t)N * T * 4 + ((size_t)v * T + t) * 4 + f] = fd;
}

// ---------------- host orchestration ----------------

extern "C" void kernel_launch(void* const* d_in, const int* in_sizes, int n_in,
                              void* d_out, int out_size, void* d_ws, size_t ws_size,
                              hipStream_t stream) {
  const float* F0        = (const float*)d_in[0];
  const int*   ei        = (const int*)d_in[1];
  const float* meshfield = (const float*)d_in[2];
  const float* mesh_W0 = (const float*)d_in[4];
  const float* mesh_b0 = (const float*)d_in[5];
  const float* mesh_Wh = (const float*)d_in[6];
  const float* mesh_bh = (const float*)d_in[7];
  const float* mesh_W9 = (const float*)d_in[8];
  const float* mesh_b9 = (const float*)d_in[9];
  const float* diff_W0 = (const float*)d_in[10];
  const float* diff_b0 = (const float*)d_in[11];
  const float* diff_Wh = (const float*)d_in[12];
  const float* diff_bh = (const float*)d_in[13];
  const float* diff_W9 = (const float*)d_in[14];
  const float* diff_b9 = (const float*)d_in[15];

  const int N = in_sizes[0] / 4;          // 30000
  const int E = in_sizes[1] / 2;          // 480000
  const int H = in_sizes[5];              // 128
  const int T = out_size / (N * 4 * 2);   // 4
  const int DEPTH = in_sizes[7] / H;      // 8
  const int Mpad = (N + 127) / 128 * 128; // 30080
  const int NB_IN = (N + 511) / 512;      // instnorm partial blocks

  const int* erow = ei;
  const int* ecol = ei + E;

  char* p = (char*)d_ws;
  auto alloc = [&](size_t bytes) { char* r = p; p += (bytes + 255) & ~(size_t)255; return r; };
  float* dinv   = (float*)alloc((size_t)N * 4);
  float* X      = (float*)alloc((size_t)N * H * 4);       // fp32 conv0 out (IN input)
  float* meshL  = (float*)alloc((size_t)N * H * 4);
  ushort* C32   = (ushort*)alloc((size_t)Mpad * 32 * 2);  // mesh conv0 input
  ushort* C160  = (ushort*)alloc((size_t)Mpad * 160 * 2); // diff conv0 input
  ushort* X16a  = (ushort*)alloc((size_t)Mpad * 128 * 2);
  ushort* X16b  = (ushort*)alloc((size_t)Mpad * 128 * 2);
  float* msg4   = (float*)alloc((size_t)N * 4 * 4);
  float* fdotp  = (float*)alloc((size_t)N * 4 * 4);
  float* fcur0  = (float*)alloc((size_t)N * 4 * 4);
  float* fcur1  = (float*)alloc((size_t)N * 4 * 4);
  float* partial= (float*)alloc((size_t)NB_IN * 256 * 4);
  float* meanv  = (float*)alloc(128 * 4);
  float* scalev = (float*)alloc(128 * 4);
  ushort* W0t_m = (ushort*)alloc((size_t)128 * 32 * 2);
  ushort* Wht_m = (ushort*)alloc((size_t)DEPTH * 128 * 128 * 2);
  ushort* W9t_m = (ushort*)alloc((size_t)128 * 128 * 2);
  ushort* W0t_d = (ushort*)alloc((size_t)128 * 160 * 2);
  ushort* Wht_d = (ushort*)alloc((size_t)DEPTH * 128 * 128 * 2);
  float* csr_w  = (float*)alloc((size_t)E * 4);
  int* cnt      = (int*)alloc((size_t)N * 4);
  int* rowptr   = (int*)alloc((size_t)(N + 1) * 4);
  int* fillc    = (int*)alloc((size_t)N * 4);
  int* csr_src  = (int*)alloc((size_t)E * 4);

  // ---- weight prep ----
  {
    dim3 g0((128 * 32 + 255) / 256, 1);
    k_wprep<<<g0, 256, 0, stream>>>(mesh_W0, W0t_m, 8, 32, 128);
    dim3 gh((128 * 128 + 255) / 256, DEPTH);
    k_wprep<<<gh, 256, 0, stream>>>(mesh_Wh, Wht_m, 128, 128, 128);
    dim3 g9((128 * 128 + 255) / 256, 1);
    k_wprep<<<g9, 256, 0, stream>>>(mesh_W9, W9t_m, 128, 128, 128);
    dim3 gd((128 * 160 + 255) / 256, 1);
    k_wprep<<<gd, 256, 0, stream>>>(diff_W0, W0t_d, 132, 160, 128);
    k_wprep<<<gh, 256, 0, stream>>>(diff_Wh, Wht_d, 128, 128, 128);
  }

  // ---- graph norm + CSR ----
  hipMemsetAsync(cnt, 0, (size_t)N * 4, stream);
  hipMemsetAsync(fillc, 0, (size_t)N * 4, stream);
  k_count<<<(E + 255) / 256, 256, 0, stream>>>(ecol, cnt, E);
  k_dinv<<<(N + 255) / 256, 256, 0, stream>>>(cnt, dinv, N);
  k_scan<<<1, 1024, 0, stream>>>(cnt, rowptr, N);
  k_fill<<<(E + 255) / 256, 256, 0, stream>>>(erow, ecol, dinv, rowptr, fillc, csr_src, csr_w, E);

  const int GCONV = Mpad / 128;

  auto conv32 = [&](const ushort* Xin, const ushort* Bt, const float* b,
                    float* oF, int aF, ushort* oB, int rB) {
    k_conv<32><<<GCONV, 256, 0, stream>>>(Xin, Bt, rowptr, csr_src, csr_w, dinv, b, oF, aF, oB, rB, N);
  };
  auto conv128 = [&](const ushort* Xin, const ushort* Bt, const float* b,
                     float* oF, int aF, ushort* oB, int rB) {
    k_conv<128><<<GCONV, 256, 0, stream>>>(Xin, Bt, rowptr, csr_src, csr_w, dinv, b, oF, aF, oB, rB, N);
  };
  auto conv160 = [&](const ushort* Xin, const ushort* Bt, const float* b,
                     float* oF, int aF, ushort* oB, int rB) {
    k_conv<160><<<GCONV, 256, 0, stream>>>(Xin, Bt, rowptr, csr_src, csr_w, dinv, b, oF, aF, oB, rB, N);
  };
  auto instnorm = [&]() {  // X fp32 -> X16a bf16 relu'd
    k_in_part<<<NB_IN, 256, 0, stream>>>(X, partial, N);
    k_in_fin<<<1, 128, 0, stream>>>(partial, NB_IN, meanv, scalev, N);
    k_in_apply<<<(N * 64 + 255) / 256, 256, 0, stream>>>(X, meanv, scalev, X16a, N);
  };

  // ---- mesh descriptor block ----
  k_cast_mesh0<<<(N * 16 + 255) / 256, 256, 0, stream>>>(meshfield, C32, N);
  conv32(C32, W0t_m, mesh_b0, X, 0, nullptr, 0);
  instnorm();
  {
    ushort* cur = X16a; ushort* nxt = X16b;
    for (int i = 0; i < DEPTH; ++i) {
      conv128(cur, Wht_m + (size_t)i * 128 * 128, mesh_bh + (size_t)i * H,
              nullptr, 0, nxt, (i < DEPTH - 1) ? 1 : 0);
      ushort* tmp = cur; cur = nxt; nxt = tmp;
    }
    conv128(cur, W9t_m, mesh_b9, meshL, 2 /*tanh*/, nullptr, 0);
  }

  // ---- recurrent differentiator ----
  k_copy<<<(N * 4 + 255) / 256, 256, 0, stream>>>(F0, fcur0, N * 4);
  float* fc = fcur0;
  float* fn = fcur1;
  float* out = (float*)d_out;

  for (int t = 0; t < T; ++t) {
    k_concat16<<<(N * 80 + 255) / 256, 256, 0, stream>>>(fc, meshL, C160, N);
    conv160(C160, W0t_d, diff_b0, X, 0, nullptr, 0);
    instnorm();
    ushort* cur = X16a; ushort* nxt = X16b;
    for (int i = 0; i < DEPTH; ++i) {
      conv128(cur, Wht_d + (size_t)i * 128 * 128, diff_bh + (size_t)i * H,
              nullptr, 0, nxt, (i < DEPTH - 1) ? 1 : 0);
      ushort* tmp = cur; cur = nxt; nxt = tmp;
    }
    k_gemm_small<<<(N + 255) / 256, 256, 0, stream>>>(cur, diff_W9, msg4, N);
    k_agg_f32<<<(N * 4 + 255) / 256, 256, 0, stream>>>(msg4, fdotp, rowptr, csr_src, csr_w,
                                                       dinv, diff_b9, N, 4);
    k_step_finish<<<(N * 4 + 255) / 256, 256, 0, stream>>>(fdotp, fc, fn, out, N, T, t);
    float* tmp = fc; fc = fn; fn = tmp;
  }
}

// Round 7
// 2170.120 us; speedup vs baseline: 2.9751x; 2.9751x over previous
//
#include <hip/hip_runtime.h>
#include <math.h>

typedef __attribute__((ext_vector_type(8))) short short8;
typedef __attribute__((ext_vector_type(4))) float f32x4;
typedef unsigned int uint;
typedef unsigned short ushort;

__device__ __forceinline__ ushort f2bf(float f) {
  union { float f; uint u; } v; v.f = f;
  uint u = v.u;
  uint r = (u + 0x7FFFu + ((u >> 16) & 1u)) >> 16;
  return (ushort)r;
}
__device__ __forceinline__ float bflo(uint u) { union { uint u; float f; } v; v.u = u << 16; return v.f; }
__device__ __forceinline__ float bfhi(uint u) { union { uint u; float f; } v; v.u = u & 0xFFFF0000u; return v.f; }
__device__ __forceinline__ uint packbf(float a, float b) { return (uint)f2bf(a) | ((uint)f2bf(b) << 16); }

// ---------------- CSR construction ----------------

static __global__ void k_count(const int* __restrict__ col, int* __restrict__ cnt, int E) {
  int e = blockIdx.x * blockDim.x + threadIdx.x;
  if (e < E) atomicAdd(&cnt[col[e]], 1);
}

static __global__ void k_dinv(const int* __restrict__ cnt, float* __restrict__ dinv, int N) {
  int v = blockIdx.x * blockDim.x + threadIdx.x;
  if (v < N) dinv[v] = rsqrtf((float)cnt[v] + 1.0f);  // +1 = self-loop
}

// two-level scan: thread-serial chunk + wave shuffle scan + wave-sum scan
static __global__ __launch_bounds__(1024) void k_scan(const int* __restrict__ cnt,
                                                      int* __restrict__ rowptr, int N) {
  const int t = threadIdx.x;
  const int per = (N + 1023) / 1024;
  int lo = t * per, hi = min(lo + per, N);
  if (lo > N) lo = N;
  if (hi < lo) hi = lo;
  int sum = 0;
  for (int i = lo; i < hi; ++i) sum += cnt[i];
  int lane = t & 63, w = t >> 6;
  int v = sum;
#pragma unroll
  for (int d = 1; d < 64; d <<= 1) {
    int u = __shfl_up(v, d, 64);
    if (lane >= d) v += u;
  }
  __shared__ int wsum[16];
  if (lane == 63) wsum[w] = v;
  __syncthreads();
  if (t < 16) {
    int x = wsum[t];
#pragma unroll
    for (int d = 1; d < 16; d <<= 1) {
      int u = __shfl_up(x, d, 64);
      if (t >= d) x += u;
    }
    wsum[t] = x;  // inclusive over waves
  }
  __syncthreads();
  int base = (w ? wsum[w - 1] : 0) + v - sum;  // exclusive prefix of this thread's chunk
  int run = base;
  for (int i = lo; i < hi; ++i) { rowptr[i] = run; run += cnt[i]; }
  if (t == 1023) rowptr[N] = run;
}

static __global__ void k_fill(const int* __restrict__ row, const int* __restrict__ col,
                              const float* __restrict__ dinv, const int* __restrict__ rowptr,
                              int* __restrict__ fillc, int* __restrict__ csr_src,
                              float* __restrict__ csr_w, int E) {
  int e = blockIdx.x * blockDim.x + threadIdx.x;
  if (e >= E) return;
  int s = row[e], d = col[e];
  int pos = rowptr[d] + atomicAdd(&fillc[d], 1);
  csr_src[pos] = s;
  csr_w[pos] = dinv[s] * dinv[d];
}

// ---------------- weight prep: W[K,Nc] fp32 -> Wt[n][kpad] bf16 ----------------

static __global__ void k_wprep(const float* __restrict__ W, ushort* __restrict__ Wt,
                               int K, int Kpad, int Nc) {
  int l = blockIdx.y;
  int idx = blockIdx.x * 256 + threadIdx.x;
  if (idx >= Nc * Kpad) return;
  int n = idx / Kpad, k = idx - n * Kpad;
  const float* Wl = W + (size_t)l * K * Nc;
  ushort* Wtl = Wt + (size_t)l * Nc * Kpad;
  Wtl[idx] = (k < K) ? f2bf(Wl[(size_t)k * Nc + n]) : (ushort)0;
}

// ---------------- MFMA GEMM: [M,128] = A[M,K] @ Bt^T, fp32 accum, flex epilogue ----------

static __global__ __launch_bounds__(256) void k_gemm16(
    const ushort* __restrict__ A, const ushort* __restrict__ Bt,  // Bt: [128 n][K]
    int K, const float* __restrict__ bias,                        // bias nullable
    float* __restrict__ outF, ushort* __restrict__ outB,          // either nullable
    int M) {
  __shared__ ushort As[128 * 40];
  __shared__ ushort Bs[128 * 40];
  const int tid = threadIdx.x;
  const int lane = tid & 63;
  const int wave = tid >> 6;
  const int wr = wave >> 1, wc = wave & 1;
  const int bm = blockIdx.x * 128;
  const int l15 = lane & 15, lk = lane >> 4;
  const int r0 = tid >> 2, o0 = tid & 3;

  f32x4 acc[4][4];
#pragma unroll
  for (int i = 0; i < 4; ++i)
#pragma unroll
    for (int j = 0; j < 4; ++j) acc[i][j] = (f32x4){0.f, 0.f, 0.f, 0.f};

  for (int k0 = 0; k0 < K; k0 += 32) {
    short8 a0 = *(const short8*)(A + (size_t)(bm + r0) * K + k0 + o0 * 8);
    short8 a1 = *(const short8*)(A + (size_t)(bm + r0 + 64) * K + k0 + o0 * 8);
    short8 b0 = *(const short8*)(Bt + (size_t)r0 * K + k0 + o0 * 8);
    short8 b1 = *(const short8*)(Bt + (size_t)(r0 + 64) * K + k0 + o0 * 8);
    __syncthreads();
    *(short8*)(As + r0 * 40 + o0 * 8) = a0;
    *(short8*)(As + (r0 + 64) * 40 + o0 * 8) = a1;
    *(short8*)(Bs + r0 * 40 + o0 * 8) = b0;
    *(short8*)(Bs + (r0 + 64) * 40 + o0 * 8) = b1;
    __syncthreads();
    short8 af[4], bfr[4];
#pragma unroll
    for (int i = 0; i < 4; ++i) {
      af[i]  = *(const short8*)(As + (wr * 64 + i * 16 + l15) * 40 + lk * 8);
      bfr[i] = *(const short8*)(Bs + (wc * 64 + i * 16 + l15) * 40 + lk * 8);
    }
#pragma unroll
    for (int i = 0; i < 4; ++i)
#pragma unroll
      for (int j = 0; j < 4; ++j)
        acc[i][j] = __builtin_amdgcn_mfma_f32_16x16x32_bf16(af[i], bfr[j], acc[i][j], 0, 0, 0);
  }
#pragma unroll
  for (int i = 0; i < 4; ++i) {
#pragma unroll
    for (int r = 0; r < 4; ++r) {
      int row = bm + wr * 64 + i * 16 + lk * 4 + r;
      if (row >= M) continue;
#pragma unroll
      for (int j = 0; j < 4; ++j) {
        int col = wc * 64 + j * 16 + l15;
        float v = acc[i][j][r] + (bias ? bias[col] : 0.f);
        if (outF) outF[(size_t)row * 128 + col] = v;
        if (outB) outB[(size_t)row * 128 + col] = f2bf(v);
      }
    }
  }
}

// ---------------- small GEMM: Y[M,4] = A16[M,128] @ W[128,4] fp32 out ----------------

static __global__ __launch_bounds__(256) void k_gemm_small(
    const ushort* __restrict__ A, const float* __restrict__ W, float* __restrict__ Y, int M) {
  __shared__ float Ws[512];
  int tid = threadIdx.x;
  for (int i = tid; i < 512; i += 256) Ws[i] = W[i];
  __syncthreads();
  int m = blockIdx.x * 256 + tid;
  if (m >= M) return;
  const uint* a = (const uint*)(A + (size_t)m * 128);
  float a0 = 0, a1 = 0, a2 = 0, a3 = 0;
#pragma unroll 8
  for (int k2 = 0; k2 < 64; ++k2) {
    uint u = a[k2];
    float x0 = bflo(u), x1 = bfhi(u);
    const float* w = Ws + k2 * 8;
    a0 += x0 * w[0] + x1 * w[4];
    a1 += x0 * w[1] + x1 * w[5];
    a2 += x0 * w[2] + x1 * w[6];
    a3 += x0 * w[3] + x1 * w[7];
  }
  float* y = Y + (size_t)m * 4;
  y[0] = a0; y[1] = a1; y[2] = a2; y[3] = a3;
}

// ---------------- aggregation (C=128, bf16): wave = 1 node, lane = 2 channels ----------
// out = bias? + dinv^2*H[v] + sum w_e H[src]; outF fp32 raw; outB bf16 with actB (0/1 relu/2 tanh)

static __global__ __launch_bounds__(256) void k_agg16(
    const ushort* __restrict__ Hm, const int* __restrict__ rowptr,
    const int* __restrict__ csr_src, const float* __restrict__ csr_w,
    const float* __restrict__ dinv, const float* __restrict__ bias,  // bias nullable
    float* __restrict__ outF,
    ushort* __restrict__ outB, int actB,
    int N) {
  int node = blockIdx.x * 4 + (threadIdx.x >> 6);
  if (node >= N) return;
  int lane = threadIdx.x & 63;
  const uint* __restrict__ Hu = (const uint*)Hm;
  float dv = dinv[node];
  float w = dv * dv;
  uint su = Hu[(size_t)node * 64 + lane];
  float acc0 = w * bflo(su), acc1 = w * bfhi(su);
  int s = rowptr[node], e = rowptr[node + 1];
  int i = s;
  for (; i + 8 <= e; i += 8) {
    int s0 = csr_src[i], s1 = csr_src[i + 1], s2 = csr_src[i + 2], s3 = csr_src[i + 3];
    int s4 = csr_src[i + 4], s5 = csr_src[i + 5], s6 = csr_src[i + 6], s7 = csr_src[i + 7];
    float w0 = csr_w[i], w1 = csr_w[i + 1], w2 = csr_w[i + 2], w3 = csr_w[i + 3];
    float w4 = csr_w[i + 4], w5 = csr_w[i + 5], w6 = csr_w[i + 6], w7 = csr_w[i + 7];
    uint u0 = Hu[(size_t)s0 * 64 + lane];
    uint u1 = Hu[(size_t)s1 * 64 + lane];
    uint u2 = Hu[(size_t)s2 * 64 + lane];
    uint u3 = Hu[(size_t)s3 * 64 + lane];
    uint u4 = Hu[(size_t)s4 * 64 + lane];
    uint u5 = Hu[(size_t)s5 * 64 + lane];
    uint u6 = Hu[(size_t)s6 * 64 + lane];
    uint u7 = Hu[(size_t)s7 * 64 + lane];
    acc0 += w0 * bflo(u0) + w1 * bflo(u1) + w2 * bflo(u2) + w3 * bflo(u3)
          + w4 * bflo(u4) + w5 * bflo(u5) + w6 * bflo(u6) + w7 * bflo(u7);
    acc1 += w0 * bfhi(u0) + w1 * bfhi(u1) + w2 * bfhi(u2) + w3 * bfhi(u3)
          + w4 * bfhi(u4) + w5 * bfhi(u5) + w6 * bfhi(u6) + w7 * bfhi(u7);
  }
  for (; i + 4 <= e; i += 4) {
    int s0 = csr_src[i], s1 = csr_src[i + 1], s2 = csr_src[i + 2], s3 = csr_src[i + 3];
    float w0 = csr_w[i], w1 = csr_w[i + 1], w2 = csr_w[i + 2], w3 = csr_w[i + 3];
    uint u0 = Hu[(size_t)s0 * 64 + lane];
    uint u1 = Hu[(size_t)s1 * 64 + lane];
    uint u2 = Hu[(size_t)s2 * 64 + lane];
    uint u3 = Hu[(size_t)s3 * 64 + lane];
    acc0 += w0 * bflo(u0) + w1 * bflo(u1) + w2 * bflo(u2) + w3 * bflo(u3);
    acc1 += w0 * bfhi(u0) + w1 * bfhi(u1) + w2 * bfhi(u2) + w3 * bfhi(u3);
  }
  for (; i < e; ++i) {
    int s0 = csr_src[i];
    float w0 = csr_w[i];
    uint u0 = Hu[(size_t)s0 * 64 + lane];
    acc0 += w0 * bflo(u0);
    acc1 += w0 * bfhi(u0);
  }
  if (bias) {
    float2 bb = *(const float2*)(bias + lane * 2);
    acc0 += bb.x; acc1 += bb.y;
  }
  if (outF) {
    *(float2*)(outF + (size_t)node * 128 + lane * 2) = make_float2(acc0, acc1);
  }
  if (outB) {
    float o0 = acc0, o1 = acc1;
    if (actB == 1) { o0 = fmaxf(o0, 0.f); o1 = fmaxf(o1, 0.f); }
    else if (actB == 2) { o0 = tanhf(o0); o1 = tanhf(o1); }
    ((uint*)outB)[(size_t)node * 64 + lane] = packbf(o0, o1);
  }
}

// ---------------- F aggregation: AggF16[v][4] = Â·F (fp32 gather, 4-wide) ----------------

static __global__ void k_aggF(const float* __restrict__ F, const int* __restrict__ rowptr,
                              const int* __restrict__ csr_src, const float* __restrict__ csr_w,
                              const float* __restrict__ dinv, ushort* __restrict__ AggF16, int N) {
  int idx = blockIdx.x * blockDim.x + threadIdx.x;  // over N*2 (float2 per thread)
  if (idx >= N * 2) return;
  int v = idx >> 1, pr = idx & 1;
  float dv = dinv[v];
  float2 x = *(const float2*)(F + (size_t)v * 4 + pr * 2);
  float a0 = dv * dv * x.x, a1 = dv * dv * x.y;
  int s = rowptr[v], e = rowptr[v + 1];
  for (int i = s; i < e; ++i) {
    float2 xs = *(const float2*)(F + (size_t)csr_src[i] * 4 + pr * 2);
    float w = csr_w[i];
    a0 += w * xs.x;
    a1 += w * xs.y;
  }
  ((uint*)AggF16)[idx] = packbf(a0, a1);
}

// ---------------- concat: C160[v] = [AggF16(4) | AggMesh16(128) | 0...] ----------------

static __global__ void k_concat160(const ushort* __restrict__ AggF16,
                                   const ushort* __restrict__ AggMesh16,
                                   ushort* __restrict__ C160, int N) {
  int idx = blockIdx.x * blockDim.x + threadIdx.x;  // over N*80 uints
  if (idx >= N * 80) return;
  int v = idx / 80, j = idx - v * 80;
  uint val = 0;
  if (j < 2) val = ((const uint*)AggF16)[(size_t)v * 2 + j];
  else if (j < 66) val = ((const uint*)AggMesh16)[(size_t)v * 64 + (j - 2)];
  ((uint*)C160)[idx] = val;
}

// ---------------- aggregation fp32, small C (C=4) ----------------

static __global__ void k_agg_f32(const float* __restrict__ Hm, float* __restrict__ Y,
                                 const int* __restrict__ rowptr, const int* __restrict__ csr_src,
                                 const float* __restrict__ csr_w, const float* __restrict__ dinv,
                                 const float* __restrict__ bias, int N, int C) {
  int idx = blockIdx.x * blockDim.x + threadIdx.x;
  if (idx >= N * C) return;
  int v = idx / C, c = idx - v * C;
  float dv = dinv[v];
  float acc = dv * dv * Hm[(size_t)v * C + c];
  int s = rowptr[v], e = rowptr[v + 1];
  for (int i = s; i < e; ++i) acc += csr_w[i] * Hm[(size_t)csr_src[i] * C + c];
  Y[idx] = acc + bias[c];
}

// ---------------- instance norm (two-stage, coalesced, atomic-free) ----------------

static __global__ __launch_bounds__(256) void k_in_part(const float* __restrict__ X,
                                                        float* __restrict__ partial, int N) {
  int tid = threadIdx.x;
  int c4 = (tid & 31) * 4;
  int rsub = tid >> 5;
  int row0 = blockIdx.x * 512 + rsub;
  int rowEnd = min(blockIdx.x * 512 + 512, N);
  float s0 = 0, s1 = 0, s2 = 0, s3 = 0, q0 = 0, q1 = 0, q2 = 0, q3 = 0;
  for (int r = row0; r < rowEnd; r += 8) {
    float4 v = *(const float4*)(X + (size_t)r * 128 + c4);
    s0 += v.x; s1 += v.y; s2 += v.z; s3 += v.w;
    q0 += v.x * v.x; q1 += v.y * v.y; q2 += v.z * v.z; q3 += v.w * v.w;
  }
  __shared__ float sb[8][132], qb[8][132];
  sb[rsub][c4] = s0; sb[rsub][c4 + 1] = s1; sb[rsub][c4 + 2] = s2; sb[rsub][c4 + 3] = s3;
  qb[rsub][c4] = q0; qb[rsub][c4 + 1] = q1; qb[rsub][c4 + 2] = q2; qb[rsub][c4 + 3] = q3;
  __syncthreads();
  if (tid < 128) {
    float ss = 0, qq = 0;
#pragma unroll
    for (int g = 0; g < 8; ++g) { ss += sb[g][tid]; qq += qb[g][tid]; }
    partial[(size_t)blockIdx.x * 256 + tid] = ss;
    partial[(size_t)blockIdx.x * 256 + 128 + tid] = qq;
  }
}

static __global__ void k_in_fin(const float* __restrict__ partial, int NB,
                                float* __restrict__ meanv, float* __restrict__ scalev, int N) {
  int c = threadIdx.x;
  if (c >= 128) return;
  float s = 0, q = 0;
  for (int b = 0; b < NB; ++b) {
    s += partial[(size_t)b * 256 + c];
    q += partial[(size_t)b * 256 + 128 + c];
  }
  float m = s / (float)N;
  float var = q / (float)N - m * m;
  meanv[c] = m;
  scalev[c] = rsqrtf(var + 1e-5f);
}

static __global__ void k_in_apply(const float* __restrict__ X, const float* __restrict__ meanv,
                                  const float* __restrict__ scalev, ushort* __restrict__ outB, int N) {
  int idx = blockIdx.x * blockDim.x + threadIdx.x;
  if (idx >= N * 64) return;
  int c2 = idx & 63;
  float2 x = *(const float2*)(X + (size_t)idx * 2);
  float2 mm = *(const float2*)(meanv + c2 * 2);
  float2 sc = *(const float2*)(scalev + c2 * 2);
  float o0 = fmaxf((x.x - mm.x) * sc.x, 0.f);
  float o1 = fmaxf((x.y - mm.y) * sc.y, 0.f);
  ((uint*)outB)[idx] = packbf(o0, o1);
}

// ---------------- misc elementwise ----------------

static __global__ void k_cast_mesh0(const float* __restrict__ MF, ushort* __restrict__ C32, int N) {
  int idx = blockIdx.x * blockDim.x + threadIdx.x;
  if (idx >= N * 16) return;
  int v = idx >> 4, c2 = idx & 15;
  int c = c2 * 2;
  float x0 = 0.f, x1 = 0.f;
  if (c < 8) { x0 = MF[v * 8 + c]; x1 = MF[v * 8 + c + 1]; }
  ((uint*)C32)[idx] = packbf(x0, x1);
}

static __global__ void k_copy(const float* __restrict__ A, float* __restrict__ B, int n) {
  int i = blockIdx.x * blockDim.x + threadIdx.x;
  if (i < n) B[i] = A[i];
}

static __global__ void k_step_finish(const float* __restrict__ fdot_pre,
                                     const float* __restrict__ Fcur, float* __restrict__ Fnext,
                                     float* __restrict__ out, int N, int T, int t) {
  int idx = blockIdx.x * blockDim.x + threadIdx.x;
  if (idx >= N * 4) return;
  int v = idx >> 2, f = idx & 3;
  float fd = tanhf(fdot_pre[idx]);
  float fn = tanhf(Fcur[idx] + fd * 0.1f);  // DT = 0.1
  Fnext[idx] = fn;
  out[((size_t)v * T + t) * 4 + f] = fn;
  out[(size_t)N * T * 4 + ((size_t)v * T + t) * 4 + f] = fd;
}

// ---------------- host orchestration ----------------

extern "C" void kernel_launch(void* const* d_in, const int* in_sizes, int n_in,
                              void* d_out, int out_size, void* d_ws, size_t ws_size,
                              hipStream_t stream) {
  const float* F0        = (const float*)d_in[0];
  const int*   ei        = (const int*)d_in[1];
  const float* meshfield = (const float*)d_in[2];
  const float* mesh_W0 = (const float*)d_in[4];
  const float* mesh_b0 = (const float*)d_in[5];
  const float* mesh_Wh = (const float*)d_in[6];
  const float* mesh_bh = (const float*)d_in[7];
  const float* mesh_W9 = (const float*)d_in[8];
  const float* mesh_b9 = (const float*)d_in[9];
  const float* diff_W0 = (const float*)d_in[10];
  const float* diff_b0 = (const float*)d_in[11];
  const float* diff_Wh = (const float*)d_in[12];
  const float* diff_bh = (const float*)d_in[13];
  const float* diff_W9 = (const float*)d_in[14];
  const float* diff_b9 = (const float*)d_in[15];

  const int N = in_sizes[0] / 4;          // 30000
  const int E = in_sizes[1] / 2;          // 480000
  const int H = in_sizes[5];              // 128
  const int T = out_size / (N * 4 * 2);   // 4
  const int DEPTH = in_sizes[7] / H;      // 8
  const int Mpad = (N + 127) / 128 * 128; // 30080
  const int NB_IN = (N + 511) / 512;

  const int* erow = ei;
  const int* ecol = ei + E;

  char* p = (char*)d_ws;
  auto alloc = [&](size_t bytes) { char* r = p; p += (bytes + 255) & ~(size_t)255; return r; };
  float* dinv     = (float*)alloc((size_t)N * 4);
  float* X        = (float*)alloc((size_t)N * H * 4);        // fp32 conv0 out (IN input)
  ushort* C32     = (ushort*)alloc((size_t)Mpad * 32 * 2);
  ushort* C160    = (ushort*)alloc((size_t)Mpad * 160 * 2);
  ushort* X16a    = (ushort*)alloc((size_t)Mpad * 128 * 2);
  ushort* X16b    = (ushort*)alloc((size_t)Mpad * 128 * 2);
  ushort* Msg16   = (ushort*)alloc((size_t)Mpad * 128 * 2);
  ushort* meshL16 = (ushort*)alloc((size_t)Mpad * 128 * 2);  // tanh(mesh latent), bf16
  ushort* AggM16  = (ushort*)alloc((size_t)Mpad * 128 * 2);  // A_hat * meshL (constant over t)
  ushort* AggF16  = (ushort*)alloc((size_t)Mpad * 4 * 2);
  float* msg4     = (float*)alloc((size_t)N * 4 * 4);
  float* fdotp    = (float*)alloc((size_t)N * 4 * 4);
  float* fcur0    = (float*)alloc((size_t)N * 4 * 4);
  float* fcur1    = (float*)alloc((size_t)N * 4 * 4);
  float* partial  = (float*)alloc((size_t)NB_IN * 256 * 4);
  float* meanv    = (float*)alloc(128 * 4);
  float* scalev   = (float*)alloc(128 * 4);
  ushort* W0t_m   = (ushort*)alloc((size_t)128 * 32 * 2);
  ushort* Wht_m   = (ushort*)alloc((size_t)DEPTH * 128 * 128 * 2);
  ushort* W9t_m   = (ushort*)alloc((size_t)128 * 128 * 2);
  ushort* W0t_d   = (ushort*)alloc((size_t)128 * 160 * 2);
  ushort* Wht_d   = (ushort*)alloc((size_t)DEPTH * 128 * 128 * 2);
  float* csr_w    = (float*)alloc((size_t)E * 4);
  int* cnt        = (int*)alloc((size_t)N * 4);
  int* rowptr     = (int*)alloc((size_t)(N + 1) * 4);
  int* fillc      = (int*)alloc((size_t)N * 4);
  int* csr_src    = (int*)alloc((size_t)E * 4);

  // ---- weight prep ----
  {
    dim3 g0((128 * 32 + 255) / 256, 1);
    k_wprep<<<g0, 256, 0, stream>>>(mesh_W0, W0t_m, 8, 32, 128);
    dim3 gh((128 * 128 + 255) / 256, DEPTH);
    k_wprep<<<gh, 256, 0, stream>>>(mesh_Wh, Wht_m, 128, 128, 128);
    dim3 g9((128 * 128 + 255) / 256, 1);
    k_wprep<<<g9, 256, 0, stream>>>(mesh_W9, W9t_m, 128, 128, 128);
    dim3 gd((128 * 160 + 255) / 256, 1);
    k_wprep<<<gd, 256, 0, stream>>>(diff_W0, W0t_d, 132, 160, 128);
    k_wprep<<<gh, 256, 0, stream>>>(diff_Wh, Wht_d, 128, 128, 128);
  }

  // ---- graph norm + CSR ----
  hipMemsetAsync(cnt, 0, (size_t)N * 4, stream);
  hipMemsetAsync(fillc, 0, (size_t)N * 4, stream);
  k_count<<<(E + 255) / 256, 256, 0, stream>>>(ecol, cnt, E);
  k_dinv<<<(N + 255) / 256, 256, 0, stream>>>(cnt, dinv, N);
  k_scan<<<1, 1024, 0, stream>>>(cnt, rowptr, N);
  k_fill<<<(E + 255) / 256, 256, 0, stream>>>(erow, ecol, dinv, rowptr, fillc, csr_src, csr_w, E);

  auto gemm = [&](const ushort* A, const ushort* Bt, int K, const float* bias,
                  float* oF, ushort* oB) {
    k_gemm16<<<Mpad / 128, 256, 0, stream>>>(A, Bt, K, bias, oF, oB, N);
  };
  auto agg = [&](const ushort* Hm, const float* bias, float* oF, ushort* oB, int actB) {
    k_agg16<<<(N + 3) / 4, 256, 0, stream>>>(Hm, rowptr, csr_src, csr_w, dinv, bias,
                                             oF, oB, actB, N);
  };
  auto instnorm = [&]() {  // X fp32 -> X16a bf16 relu'd
    k_in_part<<<NB_IN, 256, 0, stream>>>(X, partial, N);
    k_in_fin<<<1, 128, 0, stream>>>(partial, NB_IN, meanv, scalev, N);
    k_in_apply<<<(N * 64 + 255) / 256, 256, 0, stream>>>(X, meanv, scalev, X16a, N);
  };

  // ---- mesh descriptor block ----
  k_cast_mesh0<<<(N * 16 + 255) / 256, 256, 0, stream>>>(meshfield, C32, N);
  gemm(C32, W0t_m, 32, nullptr, nullptr, Msg16);
  agg(Msg16, mesh_b0, X, nullptr, 0);
  instnorm();
  {
    ushort* cur = X16a; ushort* nxt = X16b;
    for (int i = 0; i < DEPTH; ++i) {
      gemm(cur, Wht_m + (size_t)i * 128 * 128, 128, nullptr, nullptr, Msg16);
      agg(Msg16, mesh_bh + (size_t)i * H, nullptr, nxt, (i < DEPTH - 1) ? 1 : 0);
      ushort* tmp = cur; cur = nxt; nxt = tmp;
    }
    gemm(cur, W9t_m, 128, nullptr, nullptr, Msg16);
    agg(Msg16, mesh_b9, nullptr, meshL16, 2 /*tanh*/);
  }
  // constant over time: AggM16 = A_hat * meshL
  agg(meshL16, nullptr, nullptr, AggM16, 0);

  // ---- recurrent differentiator ----
  k_copy<<<(N * 4 + 255) / 256, 256, 0, stream>>>(F0, fcur0, N * 4);
  float* fc = fcur0;
  float* fn = fcur1;
  float* out = (float*)d_out;

  for (int t = 0; t < T; ++t) {
    // conv0 via linearity: X = concat(A_hat*F, A_hat*mesh) @ W0 + b0
    k_aggF<<<(N * 2 + 255) / 256, 256, 0, stream>>>(fc, rowptr, csr_src, csr_w, dinv, AggF16, N);
    k_concat160<<<(N * 80 + 255) / 256, 256, 0, stream>>>(AggF16, AggM16, C160, N);
    gemm(C160, W0t_d, 160, diff_b0, X, nullptr);
    instnorm();
    ushort* cur = X16a; ushort* nxt = X16b;
    for (int i = 0; i < DEPTH; ++i) {
      gemm(cur, Wht_d + (size_t)i * 128 * 128, 128, nullptr, nullptr, Msg16);
      agg(Msg16, diff_bh + (size_t)i * H, nullptr, nxt, (i < DEPTH - 1) ? 1 : 0);
      ushort* tmp = cur; cur = nxt; nxt = tmp;
    }
    k_gemm_small<<<(N + 255) / 256, 256, 0, stream>>>(cur, diff_W9, msg4, N);
    k_agg_f32<<<(N * 4 + 255) / 256, 256, 0, stream>>>(msg4, fdotp, rowptr, csr_src, csr_w,
                                                       dinv, diff_b9, N, 4);
    k_step_finish<<<(N * 4 + 255) / 256, 256, 0, stream>>>(fdotp, fc, fn, out, N, T, t);
    float* tmp = fc; fc = fn; fn = tmp;
  }
}